// Round 5
// baseline (896.851 us; speedup 1.0000x reference)
//
#include <hip/hip_runtime.h>
#include <hip/hip_fp16.h>

#define N_NODES 50000
#define N_EDGES 800000
#define D 64
#define NBUCK 782                    // buckets of 64 nodes: dst>>6; 782*64 = 50048
#define BCAP  1408                   // slots/bucket: mean 1024, sigma 32 -> +12 sigma
#define PCHUNK 4096
#define PBLOCKS ((N_EDGES + PCHUNK - 1) / PCHUNK)   // 196

// ---- 1. partition: counting-sort edges into 64-node dst buckets.
// LDS chunk sort -> bucket-contiguous runs -> coalesced-ish flush.
__global__ __launch_bounds__(512)
void partition_kernel(const int* __restrict__ row, const int* __restrict__ col,
                      int* __restrict__ cursor, int* __restrict__ ebuf) {
    __shared__ int hist[NBUCK];
    __shared__ int scanb[NBUCK];
    __shared__ int gbase[NBUCK];
    __shared__ int rankc[NBUCK];
    __shared__ int sortv[PCHUNK];
    __shared__ unsigned short sortb[PCHUNK];
    __shared__ int wsum[8];

    int tid = threadIdx.x, lane = tid & 63, wv = tid >> 6;
    int e0 = blockIdx.x * PCHUNK;
    int n  = min(PCHUNK, N_EDGES - e0);

    for (int i = tid; i < NBUCK; i += 512) { hist[i] = 0; rankc[i] = 0; }
    __syncthreads();
    for (int i = tid; i < n; i += 512)
        atomicAdd(&hist[col[e0 + i] >> 6], 1);
    __syncthreads();

    // exclusive scan of hist -> scanb (two 512-tiles)
    int carry = 0;
    for (int base = 0; base < NBUCK; base += 512) {
        int i = base + tid;
        int v = (i < NBUCK) ? hist[i] : 0;
        int incl = v;
        #pragma unroll
        for (int off = 1; off < 64; off <<= 1) {
            int t = __shfl_up(incl, off, 64);
            if (lane >= off) incl += t;
        }
        if (lane == 63) wsum[wv] = incl;
        __syncthreads();
        int woff = 0, tot = 0;
        #pragma unroll
        for (int k = 0; k < 8; ++k) { int s = wsum[k]; if (k < wv) woff += s; tot += s; }
        if (i < NBUCK) scanb[i] = carry + woff + incl - v;
        carry += tot;
        __syncthreads();
    }

    // reserve a global range per non-empty bucket (one atomic each)
    for (int i = tid; i < NBUCK; i += 512)
        if (hist[i] > 0) gbase[i] = atomicAdd(&cursor[i], hist[i]);
    __syncthreads();

    // rank within bucket, place into LDS-sorted order
    for (int i = tid; i < n; i += 512) {
        int d = col[e0 + i], s = row[e0 + i];
        int b = d >> 6;
        int r = atomicAdd(&rankc[b], 1);
        int slot = scanb[b] + r;
        sortv[slot] = (s << 6) | (d & 63);
        sortb[slot] = (unsigned short)b;
    }
    __syncthreads();

    // flush: consecutive slots are mostly same-bucket runs -> coalesced stores
    for (int i = tid; i < n; i += 512) {
        int b   = sortb[i];
        int idx = gbase[b] + (i - scanb[b]);
        if (idx < BCAP) ebuf[b * BCAP + idx] = sortv[i];
    }
}

// ---- 2. degrees + dinv from the packed buckets (tiny) ----
__global__ __launch_bounds__(256)
void degree_kernel(const int* __restrict__ cursor, const int* __restrict__ ebuf,
                   float* __restrict__ dinv) {
    __shared__ int hist[64];
    int tid = threadIdx.x, b = blockIdx.x;
    if (tid < 64) hist[tid] = 0;
    __syncthreads();
    int cnt = min(cursor[b], BCAP);
    const int* ep = ebuf + b * BCAP;
    for (int i = tid; i < cnt; i += 256)
        atomicAdd(&hist[ep[i] & 63], 1);
    __syncthreads();
    int node = b * 64 + tid;
    if (tid < 64 && node < N_NODES)
        dinv[node] = rsqrtf((float)(hist[tid] + 1));   // +1 self loop
}

// ---- 3. H = X @ W1 (fp32 in, fp16 out): W column in VGPRs, shfl-broadcast X ----
__global__ __launch_bounds__(256)
void gemm_kernel(const float* __restrict__ X, const float* __restrict__ W,
                 __half* __restrict__ H) {
    int tid = threadIdx.x, lane = tid & 63, wv = tid >> 6;
    float w[64];
    #pragma unroll
    for (int k = 0; k < 64; ++k) w[k] = W[k * 64 + lane];
    int node0 = blockIdx.x * 16 + wv * 4;
    #pragma unroll
    for (int r = 0; r < 4; ++r) {
        int node = node0 + r;
        float xv = X[node * 64 + lane];
        float a0 = 0.f, a1 = 0.f;
        #pragma unroll
        for (int k = 0; k < 64; k += 2) {
            a0 = fmaf(__shfl(xv, k, 64),     w[k],     a0);
            a1 = fmaf(__shfl(xv, k + 1, 64), w[k + 1], a1);
        }
        H[node * 64 + lane] = __float2half(a0 + a1);
    }
}

// ---- 4. aggregation over one 64-node bucket with an LDS fp32 accumulator.
// FUSE_W: epilogue also applies relu then multiplies by W2 (layer-2 gemm fused).
template<bool FUSE_W, typename OutT>
__global__ __launch_bounds__(512, 4)
void agg_kernel(const __half* __restrict__ H, const int* __restrict__ cursor,
                const int* __restrict__ ebuf, const float* __restrict__ dinv,
                const float* __restrict__ bias, const float* __restrict__ W,
                OutT* __restrict__ out) {
    __shared__ float acc[64 * 64];     // 16 KB
    int tid = threadIdx.x, lane = tid & 63, wv = tid >> 6;
    int b = blockIdx.x;
    for (int i = tid; i < 64 * 64; i += 512) acc[i] = 0.f;
    __syncthreads();
    int cnt = min(cursor[b], BCAP);
    const int* ep = ebuf + b * BCAP;
    for (int base = wv * 64; base < cnt; base += 512) {
        int m = min(cnt - base, 64);
        int v = 0; float w = 0.f;
        if (lane < m) { v = ep[base + lane]; w = dinv[v >> 6]; }   // batched
        int j = 0;
        for (; j + 3 < m; j += 4) {
            int   v0 = __shfl(v, j + 0, 64), v1 = __shfl(v, j + 1, 64);
            int   v2 = __shfl(v, j + 2, 64), v3 = __shfl(v, j + 3, 64);
            float w0 = __shfl(w, j + 0, 64), w1 = __shfl(w, j + 1, 64);
            float w2 = __shfl(w, j + 2, 64), w3 = __shfl(w, j + 3, 64);
            float x0 = __half2float(H[(v0 >> 6) * 64 + lane]);
            float x1 = __half2float(H[(v1 >> 6) * 64 + lane]);
            float x2 = __half2float(H[(v2 >> 6) * 64 + lane]);
            float x3 = __half2float(H[(v3 >> 6) * 64 + lane]);
            atomicAdd(&acc[(v0 & 63) * 64 + lane], w0 * x0);   // ds_add_f32, 2-way=free
            atomicAdd(&acc[(v1 & 63) * 64 + lane], w1 * x1);
            atomicAdd(&acc[(v2 & 63) * 64 + lane], w2 * x2);
            atomicAdd(&acc[(v3 & 63) * 64 + lane], w3 * x3);
        }
        for (; j < m; ++j) {
            int   vj = __shfl(v, j, 64);
            float wj = __shfl(w, j, 64);
            float xj = __half2float(H[(vj >> 6) * 64 + lane]);
            atomicAdd(&acc[(vj & 63) * 64 + lane], wj * xj);
        }
    }
    __syncthreads();
    // epilogue: 8 nodes per wave
    if constexpr (FUSE_W) {
        float wc[64];
        #pragma unroll
        for (int k = 0; k < 64; ++k) wc[k] = W[k * 64 + lane];
        for (int r = 0; r < 8; ++r) {
            int nl = wv * 8 + r, node = b * 64 + nl;
            if (node >= N_NODES) break;                        // wave-uniform
            float di   = dinv[node];
            float self = __half2float(H[node * 64 + lane]);
            float gval = di * (acc[nl * 64 + lane] + di * self) + bias[lane];
            gval = fmaxf(gval, 0.f);                           // relu
            float o0 = 0.f, o1 = 0.f;                          // (g @ W2)[lane]
            #pragma unroll
            for (int k = 0; k < 64; k += 2) {
                o0 = fmaf(__shfl(gval, k, 64),     wc[k],     o0);
                o1 = fmaf(__shfl(gval, k + 1, 64), wc[k + 1], o1);
            }
            out[node * 64 + lane] = __float2half(o0 + o1);
        }
    } else {
        for (int r = 0; r < 8; ++r) {
            int nl = wv * 8 + r, node = b * 64 + nl;
            if (node >= N_NODES) break;
            float di   = dinv[node];
            float self = __half2float(H[node * 64 + lane]);
            out[node * 64 + lane] = di * (acc[nl * 64 + lane] + di * self) + bias[lane];
        }
    }
}

extern "C" void kernel_launch(void* const* d_in, const int* in_sizes, int n_in,
                              void* d_out, int out_size, void* d_ws, size_t ws_size,
                              hipStream_t stream) {
    const float* x   = (const float*)d_in[0];
    const int*   ei  = (const int*)d_in[1];     // [2, E]: sources then targets
    const int*   row = ei;
    const int*   col = ei + N_EDGES;
    const float* W1  = (const float*)d_in[2];
    const float* b1  = (const float*)d_in[3];
    const float* W2  = (const float*)d_in[4];
    const float* b2  = (const float*)d_in[5];
    float* out = (float*)d_out;

    char* p = (char*)d_ws;
    __half* h    = (__half*)p; p += (size_t)N_NODES * D * 2;     // 6.4 MB: X@W1
    __half* h2   = (__half*)p; p += (size_t)N_NODES * D * 2;     // 6.4 MB: relu(gcn1)@W2
    float*  dinv = (float*)p;  p += (size_t)N_NODES * 4;         // 200 KB
    int*    cursor = (int*)p;  p += (size_t)NBUCK * 4;           // 3.1 KB
    int*    ebuf   = (int*)p;  p += (size_t)NBUCK * BCAP * 4;    // 4.4 MB

    hipMemsetAsync(cursor, 0, (size_t)NBUCK * 4, stream);

    partition_kernel<<<PBLOCKS, 512, 0, stream>>>(row, col, cursor, ebuf);
    degree_kernel<<<NBUCK, 256, 0, stream>>>(cursor, ebuf, dinv);
    gemm_kernel<<<N_NODES / 16, 256, 0, stream>>>(x, W1, h);
    agg_kernel<true, __half><<<NBUCK, 512, 0, stream>>>(h, cursor, ebuf, dinv, b1, W2, h2);
    agg_kernel<false, float><<<NBUCK, 512, 0, stream>>>(h2, cursor, ebuf, dinv, b2, nullptr, out);
}

// Round 6
// 349.728 us; speedup vs baseline: 2.5644x; 2.5644x over previous
//
#include <hip/hip_runtime.h>
#include <hip/hip_fp16.h>

#define N_NODES 50000
#define N_EDGES 800000
#define D 64
#define CAP 64            // slots per node; in-deg ~ Poisson(16), P(>64) ~ 1e-13
#define PBLK 125          // partition blocks
#define NPB  400          // nodes owned per partition block; 125*400 = 50000

// ---- 1. partition (owner-computes): each block owns 400 dst nodes, scans the
// whole col[] (coalesced int4), keeps matches, stores ushort src into the
// block-private bucket region (50 KB -> L2-resident, write-combined).
// Replaces memset+count+fill+dinv: counts via native LDS int atomics. ----
__global__ __launch_bounds__(1024)
void partition_kernel(const int* __restrict__ row, const int* __restrict__ col,
                      int* __restrict__ cnt_g, unsigned short* __restrict__ srcs) {
    __shared__ int cnt[NPB];
    int tid = threadIdx.x;
    int lo  = blockIdx.x * NPB;
    for (int i = tid; i < NPB; i += 1024) cnt[i] = 0;
    __syncthreads();
    const int4* c4 = (const int4*)col;
    for (int i = tid; i < N_EDGES / 4; i += 1024) {
        int4 c = c4[i];
        int dx = c.x - lo, dy = c.y - lo, dz = c.z - lo, dw = c.w - lo;
        // row[] loaded lazily, only on match (~3.2% of lanes)
        if ((unsigned)dx < NPB) {
            int p = atomicAdd(&cnt[dx], 1);
            if (p < CAP) srcs[(size_t)(lo + dx) * CAP + p] = (unsigned short)row[4 * i + 0];
        }
        if ((unsigned)dy < NPB) {
            int p = atomicAdd(&cnt[dy], 1);
            if (p < CAP) srcs[(size_t)(lo + dy) * CAP + p] = (unsigned short)row[4 * i + 1];
        }
        if ((unsigned)dz < NPB) {
            int p = atomicAdd(&cnt[dz], 1);
            if (p < CAP) srcs[(size_t)(lo + dz) * CAP + p] = (unsigned short)row[4 * i + 2];
        }
        if ((unsigned)dw < NPB) {
            int p = atomicAdd(&cnt[dw], 1);
            if (p < CAP) srcs[(size_t)(lo + dw) * CAP + p] = (unsigned short)row[4 * i + 3];
        }
    }
    __syncthreads();
    for (int i = tid; i < NPB; i += 1024) cnt_g[lo + i] = cnt[i];
}

// ---- 2. H = X @ W1 (fp32 in, fp16 out): W column in VGPRs, shfl-broadcast X ----
__global__ __launch_bounds__(256)
void gemm_kernel(const float* __restrict__ X, const float* __restrict__ W,
                 __half* __restrict__ H) {
    int tid = threadIdx.x, lane = tid & 63, wv = tid >> 6;
    float w[64];
    #pragma unroll
    for (int k = 0; k < 64; ++k) w[k] = W[k * 64 + lane];
    int node0 = blockIdx.x * 16 + wv * 4;                  // 3125*16 = 50000 exact
    #pragma unroll
    for (int r = 0; r < 4; ++r) {
        int node = node0 + r;
        float xv = X[node * 64 + lane];
        float a0 = 0.f, a1 = 0.f;
        #pragma unroll
        for (int k = 0; k < 64; k += 2) {
            a0 = fmaf(__shfl(xv, k, 64),     w[k],     a0);
            a1 = fmaf(__shfl(xv, k + 1, 64), w[k + 1], a1);
        }
        H[node * 64 + lane] = __float2half(a0 + a1);
    }
}

// ---- 3. per-node aggregate, one wave per node (proven R4 structure).
// FUSE: epilogue = bias -> relu -> @W2 (layer-2 gemm fused), fp16 out.
// else: epilogue = bias, fp32 out. dinv computed inline: rsqrt(cnt+1). ----
template<int FUSE>
__global__ __launch_bounds__(256)
void gather_kernel(const __half* __restrict__ H, const int* __restrict__ cnt,
                   const unsigned short* __restrict__ srcs,
                   const float* __restrict__ bias, const float* __restrict__ W2,
                   void* __restrict__ outp) {
    int tid = threadIdx.x, lane = tid & 63;
    int node = blockIdx.x * 4 + (tid >> 6);                // 12500*4 = 50000 exact
    int cn = cnt[node];
    float di = rsqrtf((float)(cn + 1));                    // +1 self loop
    int n = min(cn, CAP);
    const unsigned short* sp = srcs + (size_t)node * CAP;
    int s = 0; float w = 0.f;
    if (lane < n) { s = sp[lane]; w = rsqrtf((float)(cnt[s] + 1)); }   // batched
    float acc0 = di * __half2float(H[node * 64 + lane]);   // self-loop term
    float acc1 = 0.f, acc2 = 0.f, acc3 = 0.f;
    int nr = (n + 7) & ~7;                                 // pad: dummies s=0,w=0
    for (int j = 0; j < nr; j += 8) {
        int   s0 = __shfl(s, j + 0, 64), s1 = __shfl(s, j + 1, 64);
        int   s2 = __shfl(s, j + 2, 64), s3 = __shfl(s, j + 3, 64);
        int   s4 = __shfl(s, j + 4, 64), s5 = __shfl(s, j + 5, 64);
        int   s6 = __shfl(s, j + 6, 64), s7 = __shfl(s, j + 7, 64);
        float w0 = __shfl(w, j + 0, 64), w1 = __shfl(w, j + 1, 64);
        float w2 = __shfl(w, j + 2, 64), w3 = __shfl(w, j + 3, 64);
        float w4 = __shfl(w, j + 4, 64), w5 = __shfl(w, j + 5, 64);
        float w6 = __shfl(w, j + 6, 64), w7 = __shfl(w, j + 7, 64);
        float v0 = __half2float(H[s0 * 64 + lane]);
        float v1 = __half2float(H[s1 * 64 + lane]);
        float v2 = __half2float(H[s2 * 64 + lane]);
        float v3 = __half2float(H[s3 * 64 + lane]);
        float v4 = __half2float(H[s4 * 64 + lane]);
        float v5 = __half2float(H[s5 * 64 + lane]);
        float v6 = __half2float(H[s6 * 64 + lane]);
        float v7 = __half2float(H[s7 * 64 + lane]);
        acc0 += w0 * v0 + w4 * v4;
        acc1 += w1 * v1 + w5 * v5;
        acc2 += w2 * v2 + w6 * v6;
        acc3 += w3 * v3 + w7 * v7;
    }
    float gval = di * ((acc0 + acc1) + (acc2 + acc3)) + bias[lane];
    if constexpr (FUSE) {
        gval = fmaxf(gval, 0.f);                           // relu
        float wc[64];                                      // W2 column (post-loop: short live range)
        #pragma unroll
        for (int k = 0; k < 64; ++k) wc[k] = W2[k * 64 + lane];
        float o0 = 0.f, o1 = 0.f;                          // (g @ W2)[lane]
        #pragma unroll
        for (int k = 0; k < 64; k += 2) {
            o0 = fmaf(__shfl(gval, k, 64),     wc[k],     o0);
            o1 = fmaf(__shfl(gval, k + 1, 64), wc[k + 1], o1);
        }
        ((__half*)outp)[node * 64 + lane] = __float2half(o0 + o1);
    } else {
        ((float*)outp)[node * 64 + lane] = gval;
    }
}

extern "C" void kernel_launch(void* const* d_in, const int* in_sizes, int n_in,
                              void* d_out, int out_size, void* d_ws, size_t ws_size,
                              hipStream_t stream) {
    const float* x   = (const float*)d_in[0];
    const int*   ei  = (const int*)d_in[1];     // [2, E]: sources then targets
    const int*   row = ei;
    const int*   col = ei + N_EDGES;
    const float* W1  = (const float*)d_in[2];
    const float* b1  = (const float*)d_in[3];
    const float* W2  = (const float*)d_in[4];
    const float* b2  = (const float*)d_in[5];
    float* out = (float*)d_out;

    char* p = (char*)d_ws;
    __half* h   = (__half*)p;  p += (size_t)N_NODES * D * 2;          // 6.4 MB: X@W1
    __half* h2  = (__half*)p;  p += (size_t)N_NODES * D * 2;          // 6.4 MB: relu(gcn1)@W2
    int*    cnt = (int*)p;     p += (size_t)N_NODES * 4;              // 200 KB
    unsigned short* srcs = (unsigned short*)p;
    p += (size_t)N_NODES * CAP * 2;                                   // 6.4 MB

    partition_kernel<<<PBLK, 1024, 0, stream>>>(row, col, cnt, srcs);
    gemm_kernel<<<N_NODES / 16, 256, 0, stream>>>(x, W1, h);
    gather_kernel<1><<<N_NODES / 4, 256, 0, stream>>>(h, cnt, srcs, b1, W2, h2);
    gather_kernel<0><<<N_NODES / 4, 256, 0, stream>>>(h2, cnt, srcs, b2, nullptr, out);
}

// Round 7
// 225.679 us; speedup vs baseline: 3.9740x; 1.5497x over previous
//
#include <hip/hip_runtime.h>
#include <hip/hip_fp16.h>

#define N_NODES 50000
#define N_EDGES 800000
#define D 64
#define RANGES 8
#define SLICES 16
#define NPB (N_NODES / RANGES)    // 6250 nodes per range
#define I4S (N_EDGES / SLICES / 4)  // 12500 int4 per slice
#define CAPS 12                   // slots per (node,slice): lambda=1, P(>12)~6e-11
#define CAP  48                   // compacted slots per node: deg~Poisson(16)

// ---- 1. partition: block (r,s) scans edge-slice s, keeps dsts in range r,
// stores ushort src into its PRIVATE dense sub-bucket region. LDS cursors,
// zero global atomics, dense writes. Total col+row read = RANGES * 6.4 MB. ----
__global__ __launch_bounds__(1024)
void partition_kernel(const int* __restrict__ row, const int* __restrict__ col,
                      unsigned char* __restrict__ cnt8,
                      unsigned short* __restrict__ ebuf) {
    __shared__ int cur[NPB];      // 25 KB
    int tid = threadIdx.x;
    int r   = blockIdx.x & (RANGES - 1);
    int s   = blockIdx.x / RANGES;
    int lo  = r * NPB;
    for (int i = tid; i < NPB; i += 1024) cur[i] = 0;
    __syncthreads();
    const int4* c4 = (const int4*)col;
    const int4* r4 = (const int4*)row;
    size_t ebase = (size_t)s * N_NODES * CAPS;
    for (int i = s * I4S + tid; i < (s + 1) * I4S; i += 1024) {
        int4 c  = c4[i];
        int4 rr = r4[i];
        int dx = c.x - lo, dy = c.y - lo, dz = c.z - lo, dw = c.w - lo;
        if ((unsigned)dx < NPB) {
            int p = atomicAdd(&cur[dx], 1);
            if (p < CAPS) ebuf[ebase + (size_t)(lo + dx) * CAPS + p] = (unsigned short)rr.x;
        }
        if ((unsigned)dy < NPB) {
            int p = atomicAdd(&cur[dy], 1);
            if (p < CAPS) ebuf[ebase + (size_t)(lo + dy) * CAPS + p] = (unsigned short)rr.y;
        }
        if ((unsigned)dz < NPB) {
            int p = atomicAdd(&cur[dz], 1);
            if (p < CAPS) ebuf[ebase + (size_t)(lo + dz) * CAPS + p] = (unsigned short)rr.z;
        }
        if ((unsigned)dw < NPB) {
            int p = atomicAdd(&cur[dw], 1);
            if (p < CAPS) ebuf[ebase + (size_t)(lo + dw) * CAPS + p] = (unsigned short)rr.w;
        }
    }
    __syncthreads();
    for (int i = tid; i < NPB; i += 1024)
        cnt8[(size_t)s * N_NODES + lo + i] = (unsigned char)min(cur[i], CAPS);
}

// ---- 2. compact: one wave per node. Merge 16 sub-buckets -> dense 96B row,
// compute deg -> dinv. Pays the sub-bucket slop once; gathers then read 1-2
// lines per node. ----
__global__ __launch_bounds__(256)
void compact_kernel(const unsigned char* __restrict__ cnt8,
                    const unsigned short* __restrict__ ebuf,
                    unsigned short* __restrict__ srcs,
                    float* __restrict__ dinv, int* __restrict__ cntf) {
    int tid = threadIdx.x, lane = tid & 63;
    int node = blockIdx.x * 4 + (tid >> 6);          // 12500*4 = 50000 exact
    int c = 0;
    if (lane < SLICES) c = cnt8[(size_t)lane * N_NODES + node];
    int pin = c;                                     // inclusive prefix, lanes<16
    #pragma unroll
    for (int off = 1; off < SLICES; off <<= 1) {
        int t = __shfl_up(pin, off, 64);
        if (lane >= off && lane < SLICES) pin += t;
    }
    int n = __shfl(pin, SLICES - 1, 64);
    int kk = 0, pp = 0;                              // slice + offset for edge 'lane'
    #pragma unroll
    for (int k = 0; k < SLICES; ++k) {
        int Pk = __shfl(pin, k, 64);
        if (lane >= Pk) { kk = k + 1; pp = Pk; }
    }
    unsigned short v = 0;
    if (lane < n && lane < CAP)
        v = ebuf[((size_t)kk * N_NODES + node) * CAPS + (lane - pp)];
    if (lane < CAP) srcs[(size_t)node * CAP + lane] = v;   // dense 96B row, 0-padded
    if (lane == 0) {
        cntf[node] = min(n, CAP);
        dinv[node] = rsqrtf((float)(n + 1));         // +1 self loop
    }
}

// ---- 3. H = X @ W1 (fp32 in, fp16 out): W column in VGPRs, shfl-broadcast X ----
__global__ __launch_bounds__(256)
void gemm_kernel(const float* __restrict__ X, const float* __restrict__ W,
                 __half* __restrict__ H) {
    int tid = threadIdx.x, lane = tid & 63, wv = tid >> 6;
    float w[64];
    #pragma unroll
    for (int k = 0; k < 64; ++k) w[k] = W[k * 64 + lane];
    int node0 = blockIdx.x * 16 + wv * 4;            // 3125*16 = 50000 exact
    #pragma unroll
    for (int r = 0; r < 4; ++r) {
        int node = node0 + r;
        float xv = X[node * 64 + lane];
        float a0 = 0.f, a1 = 0.f;
        #pragma unroll
        for (int k = 0; k < 64; k += 2) {
            a0 = fmaf(__shfl(xv, k, 64),     w[k],     a0);
            a1 = fmaf(__shfl(xv, k + 1, 64), w[k + 1], a1);
        }
        H[node * 64 + lane] = __float2half(a0 + a1);
    }
}

// ---- 4. per-node aggregate, one wave per node (R4 structure).
// FUSE: epilogue = bias -> relu -> @W2, fp16 out. else: bias, fp32 out. ----
template<int FUSE>
__global__ __launch_bounds__(256)
void gather_kernel(const __half* __restrict__ H, const int* __restrict__ cnt,
                   const unsigned short* __restrict__ srcs,
                   const float* __restrict__ dinv,
                   const float* __restrict__ bias, const float* __restrict__ W2,
                   void* __restrict__ outp) {
    int tid = threadIdx.x, lane = tid & 63;
    int node = blockIdx.x * 4 + (tid >> 6);          // 12500*4 = 50000 exact
    int n = cnt[node];
    float di = dinv[node];
    const unsigned short* sp = srcs + (size_t)node * CAP;
    int s = 0; float w = 0.f;
    if (lane < n) { s = sp[lane]; w = dinv[s]; }     // one batched load
    float acc0 = di * __half2float(H[node * 64 + lane]);   // self-loop term
    float acc1 = 0.f, acc2 = 0.f, acc3 = 0.f;
    int nr = (n + 7) & ~7;                           // pad: dummies s=0,w=0
    for (int j = 0; j < nr; j += 8) {
        int   s0 = __shfl(s, j + 0, 64), s1 = __shfl(s, j + 1, 64);
        int   s2 = __shfl(s, j + 2, 64), s3 = __shfl(s, j + 3, 64);
        int   s4 = __shfl(s, j + 4, 64), s5 = __shfl(s, j + 5, 64);
        int   s6 = __shfl(s, j + 6, 64), s7 = __shfl(s, j + 7, 64);
        float w0 = __shfl(w, j + 0, 64), w1 = __shfl(w, j + 1, 64);
        float w2 = __shfl(w, j + 2, 64), w3 = __shfl(w, j + 3, 64);
        float w4 = __shfl(w, j + 4, 64), w5 = __shfl(w, j + 5, 64);
        float w6 = __shfl(w, j + 6, 64), w7 = __shfl(w, j + 7, 64);
        float v0 = __half2float(H[s0 * 64 + lane]);
        float v1 = __half2float(H[s1 * 64 + lane]);
        float v2 = __half2float(H[s2 * 64 + lane]);
        float v3 = __half2float(H[s3 * 64 + lane]);
        float v4 = __half2float(H[s4 * 64 + lane]);
        float v5 = __half2float(H[s5 * 64 + lane]);
        float v6 = __half2float(H[s6 * 64 + lane]);
        float v7 = __half2float(H[s7 * 64 + lane]);
        acc0 += w0 * v0 + w4 * v4;
        acc1 += w1 * v1 + w5 * v5;
        acc2 += w2 * v2 + w6 * v6;
        acc3 += w3 * v3 + w7 * v7;
    }
    float gval = di * ((acc0 + acc1) + (acc2 + acc3)) + bias[lane];
    if constexpr (FUSE) {
        gval = fmaxf(gval, 0.f);                     // relu
        float wc[64];
        #pragma unroll
        for (int k = 0; k < 64; ++k) wc[k] = W2[k * 64 + lane];
        float o0 = 0.f, o1 = 0.f;                    // (g @ W2)[lane]
        #pragma unroll
        for (int k = 0; k < 64; k += 2) {
            o0 = fmaf(__shfl(gval, k, 64),     wc[k],     o0);
            o1 = fmaf(__shfl(gval, k + 1, 64), wc[k + 1], o1);
        }
        ((__half*)outp)[node * 64 + lane] = __float2half(o0 + o1);
    } else {
        ((float*)outp)[node * 64 + lane] = gval;
    }
}

extern "C" void kernel_launch(void* const* d_in, const int* in_sizes, int n_in,
                              void* d_out, int out_size, void* d_ws, size_t ws_size,
                              hipStream_t stream) {
    const float* x   = (const float*)d_in[0];
    const int*   ei  = (const int*)d_in[1];     // [2, E]: sources then targets
    const int*   row = ei;
    const int*   col = ei + N_EDGES;
    const float* W1  = (const float*)d_in[2];
    const float* b1  = (const float*)d_in[3];
    const float* W2  = (const float*)d_in[4];
    const float* b2  = (const float*)d_in[5];
    float* out = (float*)d_out;

    // ws layout (31.6 MB). Region A is reused: ebuf+cnt8 die after compact,
    // h2 (gather1 output) overlays them.
    char* p = (char*)d_ws;
    __half* h = (__half*)p;            p += (size_t)N_NODES * D * 2;        // 6.4 MB
    char* A = p;                       p += 20000000;                       // 20 MB
    unsigned short* ebuf = (unsigned short*)A;               // 19.2 MB, phase 1 only
    unsigned char*  cnt8 = (unsigned char*)(A + 19200000);   // 0.8 MB, phase 1 only
    __half* h2 = (__half*)A;                                 // 6.4 MB, phase 2
    unsigned short* srcs = (unsigned short*)p; p += (size_t)N_NODES * CAP * 2; // 4.8 MB
    float* dinv = (float*)p;           p += (size_t)N_NODES * 4;            // 0.2 MB
    int*   cntf = (int*)p;             p += (size_t)N_NODES * 4;            // 0.2 MB

    partition_kernel<<<RANGES * SLICES, 1024, 0, stream>>>(row, col, cnt8, ebuf);
    compact_kernel<<<N_NODES / 4, 256, 0, stream>>>(cnt8, ebuf, srcs, dinv, cntf);
    gemm_kernel<<<N_NODES / 16, 256, 0, stream>>>(x, W1, h);
    gather_kernel<1><<<N_NODES / 4, 256, 0, stream>>>(h, cntf, srcs, dinv, b1, W2, h2);
    gather_kernel<0><<<N_NODES / 4, 256, 0, stream>>>(h2, cntf, srcs, dinv, b2, nullptr, out);
}

// Round 8
// 213.227 us; speedup vs baseline: 4.2061x; 1.0584x over previous
//
#include <hip/hip_runtime.h>
#include <hip/hip_fp16.h>

#define N_NODES 50000
#define N_EDGES 800000
#define D 64
#define RANGES 8
#define SLICES 16
#define NPB (N_NODES / RANGES)    // 6250 nodes per range
#define I4S (N_EDGES / SLICES / 4)  // 12500 int4 per slice
#define CAPS 12                   // slots per (node,slice): lambda=1, P(>12)~6e-11
#define CAP  48                   // compacted slots per node: deg~Poisson(16)

// ---- 1. partition: block (r,s) scans edge-slice s, keeps dsts in range r,
// stores ushort src into its PRIVATE dense sub-bucket region. LDS cursors,
// zero global atomics, dense writes. Total col+row read = RANGES * 6.4 MB. ----
__global__ __launch_bounds__(1024)
void partition_kernel(const int* __restrict__ row, const int* __restrict__ col,
                      unsigned char* __restrict__ cnt8,
                      unsigned short* __restrict__ ebuf) {
    __shared__ int cur[NPB];      // 25 KB
    int tid = threadIdx.x;
    int r   = blockIdx.x & (RANGES - 1);
    int s   = blockIdx.x / RANGES;
    int lo  = r * NPB;
    for (int i = tid; i < NPB; i += 1024) cur[i] = 0;
    __syncthreads();
    const int4* c4 = (const int4*)col;
    const int4* r4 = (const int4*)row;
    size_t ebase = (size_t)s * N_NODES * CAPS;
    for (int i = s * I4S + tid; i < (s + 1) * I4S; i += 1024) {
        int4 c  = c4[i];
        int4 rr = r4[i];
        int dx = c.x - lo, dy = c.y - lo, dz = c.z - lo, dw = c.w - lo;
        if ((unsigned)dx < NPB) {
            int p = atomicAdd(&cur[dx], 1);
            if (p < CAPS) ebuf[ebase + (size_t)(lo + dx) * CAPS + p] = (unsigned short)rr.x;
        }
        if ((unsigned)dy < NPB) {
            int p = atomicAdd(&cur[dy], 1);
            if (p < CAPS) ebuf[ebase + (size_t)(lo + dy) * CAPS + p] = (unsigned short)rr.y;
        }
        if ((unsigned)dz < NPB) {
            int p = atomicAdd(&cur[dz], 1);
            if (p < CAPS) ebuf[ebase + (size_t)(lo + dz) * CAPS + p] = (unsigned short)rr.z;
        }
        if ((unsigned)dw < NPB) {
            int p = atomicAdd(&cur[dw], 1);
            if (p < CAPS) ebuf[ebase + (size_t)(lo + dw) * CAPS + p] = (unsigned short)rr.w;
        }
    }
    __syncthreads();
    for (int i = tid; i < NPB; i += 1024)
        cnt8[(size_t)s * N_NODES + lo + i] = (unsigned char)min(cur[i], CAPS);
}

// ---- 2. compact: one wave per node. Merge 16 sub-buckets -> dense 96B row,
// compute deg -> dinv. ----
__global__ __launch_bounds__(256)
void compact_kernel(const unsigned char* __restrict__ cnt8,
                    const unsigned short* __restrict__ ebuf,
                    unsigned short* __restrict__ srcs,
                    float* __restrict__ dinv, int* __restrict__ cntf) {
    int tid = threadIdx.x, lane = tid & 63;
    int node = blockIdx.x * 4 + (tid >> 6);          // 12500*4 = 50000 exact
    int c = 0;
    if (lane < SLICES) c = cnt8[(size_t)lane * N_NODES + node];
    int pin = c;                                     // inclusive prefix, lanes<16
    #pragma unroll
    for (int off = 1; off < SLICES; off <<= 1) {
        int t = __shfl_up(pin, off, 64);
        if (lane >= off && lane < SLICES) pin += t;
    }
    int n = __shfl(pin, SLICES - 1, 64);
    int kk = 0, pp = 0;                              // slice + offset for edge 'lane'
    #pragma unroll
    for (int k = 0; k < SLICES; ++k) {
        int Pk = __shfl(pin, k, 64);
        if (lane >= Pk) { kk = k + 1; pp = Pk; }
    }
    unsigned short v = 0;
    if (lane < n && lane < CAP)
        v = ebuf[((size_t)kk * N_NODES + node) * CAPS + (lane - pp)];
    if (lane < CAP) srcs[(size_t)node * CAP + lane] = v;   // dense 96B row, 0-padded
    if (lane == 0) {
        cntf[node] = min(n, CAP);
        dinv[node] = rsqrtf((float)(n + 1));         // +1 self loop
    }
}

// ---- 3. H = X @ W1 (fp32 in, fp16 out): W column in VGPRs, shfl-broadcast X ----
__global__ __launch_bounds__(256)
void gemm_kernel(const float* __restrict__ X, const float* __restrict__ W,
                 __half* __restrict__ H) {
    int tid = threadIdx.x, lane = tid & 63, wv = tid >> 6;
    float w[64];
    #pragma unroll
    for (int k = 0; k < 64; ++k) w[k] = W[k * 64 + lane];
    int node0 = blockIdx.x * 16 + wv * 4;            // 3125*16 = 50000 exact
    #pragma unroll
    for (int r = 0; r < 4; ++r) {
        int node = node0 + r;
        float xv = X[node * 64 + lane];
        float a0 = 0.f, a1 = 0.f;
        #pragma unroll
        for (int k = 0; k < 64; k += 2) {
            a0 = fmaf(__shfl(xv, k, 64),     w[k],     a0);
            a1 = fmaf(__shfl(xv, k + 1, 64), w[k + 1], a1);
        }
        H[node * 64 + lane] = __float2half(a0 + a1);
    }
}

// ---- 4. per-node aggregate, one wave per node, HALF-WAVE PER ROW:
// lane loads half2 (4B) so one load instruction fetches rows for TWO edges
// (lanes 0-31: edge j, lanes 32-63: edge j+1). 8 unrolled loads = 16 edges
// in flight. (src, fp16 weight) packed in one reg -> 1 shuffle per edge.
// FUSE: epilogue = bias -> relu -> @W2, fp16 out. else: bias, fp32 out. ----
template<int FUSE>
__global__ __launch_bounds__(256)
void gather_kernel(const __half* __restrict__ H, const int* __restrict__ cnt,
                   const unsigned short* __restrict__ srcs,
                   const float* __restrict__ dinv,
                   const float* __restrict__ bias, const float* __restrict__ W2,
                   void* __restrict__ outp) {
    int tid = threadIdx.x, lane = tid & 63;
    int half = lane >> 5, sub = lane & 31;
    int node = blockIdx.x * 4 + (tid >> 6);          // 12500*4 = 50000 exact
    int n = cnt[node];
    float di = dinv[node];
    const unsigned short* sp = srcs + (size_t)node * CAP;
    int e = 0;
    if (lane < n) {                                  // batched setup (paid once)
        int s = sp[lane];
        float w = dinv[s];
        e = s | (((int)__half_as_ushort(__float2half(w))) << 16);
    }
    const __half2* H2 = (const __half2*)H;
    float2 self2 = __half22float2(H2[(size_t)node * 32 + sub]);
    float sw = (half == 0) ? di : 0.f;               // self only in half 0
    float ax = sw * self2.x, ay = sw * self2.y;
    int i0 = half;                                   // edge idx for this half
    int nr = (n + 15) & ~15;                         // pad: dummies e=0 -> w=+0
    for (int base = 0; base < nr; base += 16) {
        int b0 = base + i0;
        int q0 = __shfl(e, b0 + 0,  64), q1 = __shfl(e, b0 + 2,  64);
        int q2 = __shfl(e, b0 + 4,  64), q3 = __shfl(e, b0 + 6,  64);
        int q4 = __shfl(e, b0 + 8,  64), q5 = __shfl(e, b0 + 10, 64);
        int q6 = __shfl(e, b0 + 12, 64), q7 = __shfl(e, b0 + 14, 64);
        float2 v0 = __half22float2(H2[(size_t)(q0 & 0xFFFF) * 32 + sub]);
        float2 v1 = __half22float2(H2[(size_t)(q1 & 0xFFFF) * 32 + sub]);
        float2 v2 = __half22float2(H2[(size_t)(q2 & 0xFFFF) * 32 + sub]);
        float2 v3 = __half22float2(H2[(size_t)(q3 & 0xFFFF) * 32 + sub]);
        float2 v4 = __half22float2(H2[(size_t)(q4 & 0xFFFF) * 32 + sub]);
        float2 v5 = __half22float2(H2[(size_t)(q5 & 0xFFFF) * 32 + sub]);
        float2 v6 = __half22float2(H2[(size_t)(q6 & 0xFFFF) * 32 + sub]);
        float2 v7 = __half22float2(H2[(size_t)(q7 & 0xFFFF) * 32 + sub]);
        float w0 = __half2float(__ushort_as_half((unsigned short)((unsigned)q0 >> 16)));
        float w1 = __half2float(__ushort_as_half((unsigned short)((unsigned)q1 >> 16)));
        float w2 = __half2float(__ushort_as_half((unsigned short)((unsigned)q2 >> 16)));
        float w3 = __half2float(__ushort_as_half((unsigned short)((unsigned)q3 >> 16)));
        float w4 = __half2float(__ushort_as_half((unsigned short)((unsigned)q4 >> 16)));
        float w5 = __half2float(__ushort_as_half((unsigned short)((unsigned)q5 >> 16)));
        float w6 = __half2float(__ushort_as_half((unsigned short)((unsigned)q6 >> 16)));
        float w7 = __half2float(__ushort_as_half((unsigned short)((unsigned)q7 >> 16)));
        ax = fmaf(w0, v0.x, ax); ay = fmaf(w0, v0.y, ay);
        ax = fmaf(w1, v1.x, ax); ay = fmaf(w1, v1.y, ay);
        ax = fmaf(w2, v2.x, ax); ay = fmaf(w2, v2.y, ay);
        ax = fmaf(w3, v3.x, ax); ay = fmaf(w3, v3.y, ay);
        ax = fmaf(w4, v4.x, ax); ay = fmaf(w4, v4.y, ay);
        ax = fmaf(w5, v5.x, ax); ay = fmaf(w5, v5.y, ay);
        ax = fmaf(w6, v6.x, ax); ay = fmaf(w6, v6.y, ay);
        ax = fmaf(w7, v7.x, ax); ay = fmaf(w7, v7.y, ay);
    }
    // combine the two halves, then redistribute to col = lane
    ax += __shfl_xor(ax, 32, 64);
    ay += __shfl_xor(ay, 32, 64);
    float cx = __shfl(ax, lane >> 1, 64);
    float cy = __shfl(ay, lane >> 1, 64);
    float sum = (lane & 1) ? cy : cx;
    float gval = di * sum + bias[lane];
    if constexpr (FUSE) {
        gval = fmaxf(gval, 0.f);                     // relu
        float wc[64];
        #pragma unroll
        for (int k = 0; k < 64; ++k) wc[k] = W2[k * 64 + lane];
        float o0 = 0.f, o1 = 0.f;                    // (g @ W2)[lane]
        #pragma unroll
        for (int k = 0; k < 64; k += 2) {
            o0 = fmaf(__shfl(gval, k, 64),     wc[k],     o0);
            o1 = fmaf(__shfl(gval, k + 1, 64), wc[k + 1], o1);
        }
        ((__half*)outp)[node * 64 + lane] = __float2half(o0 + o1);
    } else {
        ((float*)outp)[node * 64 + lane] = gval;
    }
}

extern "C" void kernel_launch(void* const* d_in, const int* in_sizes, int n_in,
                              void* d_out, int out_size, void* d_ws, size_t ws_size,
                              hipStream_t stream) {
    const float* x   = (const float*)d_in[0];
    const int*   ei  = (const int*)d_in[1];     // [2, E]: sources then targets
    const int*   row = ei;
    const int*   col = ei + N_EDGES;
    const float* W1  = (const float*)d_in[2];
    const float* b1  = (const float*)d_in[3];
    const float* W2  = (const float*)d_in[4];
    const float* b2  = (const float*)d_in[5];
    float* out = (float*)d_out;

    // ws layout (31.6 MB, proven R7). Region A reused: ebuf+cnt8 die after
    // compact, h2 (gather1 output) overlays them.
    char* p = (char*)d_ws;
    __half* h = (__half*)p;            p += (size_t)N_NODES * D * 2;        // 6.4 MB
    char* A = p;                       p += 20000000;                       // 20 MB
    unsigned short* ebuf = (unsigned short*)A;               // 19.2 MB, phase 1 only
    unsigned char*  cnt8 = (unsigned char*)(A + 19200000);   // 0.8 MB, phase 1 only
    __half* h2 = (__half*)A;                                 // 6.4 MB, phase 2
    unsigned short* srcs = (unsigned short*)p; p += (size_t)N_NODES * CAP * 2; // 4.8 MB
    float* dinv = (float*)p;           p += (size_t)N_NODES * 4;            // 0.2 MB
    int*   cntf = (int*)p;             p += (size_t)N_NODES * 4;            // 0.2 MB

    partition_kernel<<<RANGES * SLICES, 1024, 0, stream>>>(row, col, cnt8, ebuf);
    compact_kernel<<<N_NODES / 4, 256, 0, stream>>>(cnt8, ebuf, srcs, dinv, cntf);
    gemm_kernel<<<N_NODES / 16, 256, 0, stream>>>(x, W1, h);
    gather_kernel<1><<<N_NODES / 4, 256, 0, stream>>>(h, cntf, srcs, dinv, b1, W2, h2);
    gather_kernel<0><<<N_NODES / 4, 256, 0, stream>>>(h2, cntf, srcs, dinv, b2, nullptr, out);
}